// Round 3
// baseline (5963.871 us; speedup 1.0000x reference)
//
#include <hip/hip_runtime.h>
#include <cstdint>
#include <cstddef>

#define BATCH   8
#define NPTS    8192
#define NPOINT  2048
#define NSAMPLE 64
#define K0      67      // 3 + 64 input channels
#define K0P     68      // padded row stride (16B-aligned rows: 68*4=272=17*16)
#define C2      128

// Exact-order squared distance, matching XLA/numpy: ((dx*dx + dy*dy) + dz*dz),
// separate mul/add (no FMA contraction), round-to-nearest f32.
__device__ __forceinline__ float d2e(float ax, float ay, float az,
                                     float bx, float by, float bz) {
#pragma clang fp contract(off)
  float dx = ax - bx;
  float dy = ay - by;
  float dz = az - bz;
  float t0 = dx * dx;
  float t1 = dy * dy;
  float t2 = dz * dz;
  return (t0 + t1) + t2;
}

__device__ __forceinline__ float wave_fmax(float v) {
#pragma unroll
  for (int m = 1; m < 64; m <<= 1) v = fmaxf(v, __shfl_xor(v, m, 64));
  return v;
}

__device__ __forceinline__ int quant4(float v) {
  return (v < -0.6745f) ? 0 : (v < 0.f) ? 1 : (v < 0.6745f) ? 2 : 3;
}

// ---------------- FPS: bucketed-pruned serial argmax -------------------------
// One block per batch. Points counting-sorted into 128 spatially-tight buckets
// of 64 (serpentine cell order). Wave w owns buckets {j*8+w}, lane l owns
// sorted point bkt*64+l. Bounding-sphere lower bound provably skips buckets
// whose dd cannot change (margins >> f32 rounding) -> dd stays bit-exact.
__global__ __launch_bounds__(512) void fps_kernel(const float* __restrict__ xyz,
                                                  float* __restrict__ out_xyz,
                                                  float* __restrict__ out_inds) {
  const int b = blockIdx.x;
  const int tid = threadIdx.x;
  const int lane = tid & 63, w = tid >> 6;

  __shared__ float ssx[NPTS], ssy[NPTS], ssz[NPTS];
  __shared__ int   soi[NPTS];
  __shared__ float4 bgeo[128];     // cx, cy, cz, r (over-estimated)
  __shared__ float  bcmax[128];    // exact per-bucket max dd
  __shared__ float  mred[2][8];
  __shared__ int    cand[2];
  __shared__ int    hist[64], cbase[64], ccnt[64];

  const float* xb = xyz + (size_t)b * NPTS * 3;
  const float q0x = xb[0], q0y = xb[1], q0z = xb[2];

  if (tid < 64) { hist[tid] = 0; ccnt[tid] = 0; }
  if (tid == 0) { cand[0] = 0x7FFFFFFF; cand[1] = 0x7FFFFFFF; }
  __syncthreads();

  // --- counting sort by serpentine-ordered 4x4x4 quartile cells
  float lx[16], ly[16], lz[16];
  int lc[16];
#pragma unroll
  for (int k = 0; k < 16; k++) {
    int i = tid + k * 512;
    float x = xb[i * 3 + 0], y = xb[i * 3 + 1], z = xb[i * 3 + 2];
    lx[k] = x; ly[k] = y; lz[k] = z;
    int qx_ = quant4(x), qy_ = quant4(y), qz_ = quant4(z);
    int yy = (qx_ & 1) ? 3 - qy_ : qy_;
    int zz = ((qx_ ^ yy) & 1) ? 3 - qz_ : qz_;   // serpentine: adjacent cells touch
    int cell = qx_ * 16 + yy * 4 + zz;
    lc[k] = cell;
    atomicAdd(&hist[cell], 1);
  }
  __syncthreads();
  if (tid == 0) {
    int s = 0;
    for (int c = 0; c < 64; c++) { cbase[c] = s; s += hist[c]; }
  }
  __syncthreads();
#pragma unroll
  for (int k = 0; k < 16; k++) {
    int pos = cbase[lc[k]] + atomicAdd(&ccnt[lc[k]], 1);
    ssx[pos] = lx[k]; ssy[pos] = ly[k]; ssz[pos] = lz[k];
    soi[pos] = tid + k * 512;
  }
  __syncthreads();

  // --- load owned points, init dd, bucket geometry (bounding box -> sphere)
  float px[16], py[16], pz[16], dd[16], cmaxr[16];
  int oi[16];
#pragma unroll
  for (int j = 0; j < 16; j++) {
    int i = j * 512 + tid;
    px[j] = ssx[i]; py[j] = ssy[i]; pz[j] = ssz[i]; oi[j] = soi[i];
    dd[j] = d2e(px[j], py[j], pz[j], q0x, q0y, q0z);
    float xhi = wave_fmax(px[j]), xlo = -wave_fmax(-px[j]);
    float yhi = wave_fmax(py[j]), ylo = -wave_fmax(-py[j]);
    float zhi = wave_fmax(pz[j]), zlo = -wave_fmax(-pz[j]);
    float cx = 0.5f * (xlo + xhi), cy = 0.5f * (ylo + yhi), cz = 0.5f * (zlo + zhi);
    float hx = fmaxf(xhi - cx, cx - xlo);
    float hy = fmaxf(yhi - cy, cy - ylo);
    float hz = fmaxf(zhi - cz, cz - zlo);
    float br = sqrtf(hx * hx + hy * hy + hz * hz) * 1.0002f + 1e-6f;
    cmaxr[j] = wave_fmax(dd[j]);
    if (lane == 0) {
      bgeo[j * 8 + w] = make_float4(cx, cy, cz, br);
      bcmax[j * 8 + w] = cmaxr[j];
    }
  }
  if (tid == 0) {
    out_inds[b * NPOINT] = 0.f;
    out_xyz[(size_t)b * NPOINT * 3 + 0] = q0x;
    out_xyz[(size_t)b * NPOINT * 3 + 1] = q0y;
    out_xyz[(size_t)b * NPOINT * 3 + 2] = q0z;
  }
  __syncthreads();

  float qx = q0x, qy = q0y, qz = q0z;
  for (int t = 1; t < NPOINT; ++t) {
    const int par = t & 1;
    // --- check phase: lanes (mod 16) test one owned bucket each
    int jj = lane & 15;
    float4 g = bgeo[jj * 8 + w];
    float cm = bcmax[jj * 8 + w];
    float s = sqrtf(d2e(qx, qy, qz, g.x, g.y, g.z)) * 0.9999f;
    float tt = s - g.w;
    bool dirty = !((tt > 0.f) && (tt * tt * 0.998f > cm));
    unsigned dmask = (unsigned)__ballot(dirty) & 0xFFFFu;

    // --- update dirty buckets (wave-uniform scalar branches, static j)
    float mw = 0.f;
#pragma unroll
    for (int j = 0; j < 16; j++) {
      if (dmask & (1u << j)) {
        float nd = fminf(dd[j], d2e(px[j], py[j], pz[j], qx, qy, qz));
        dd[j] = nd;
        float v = wave_fmax(nd);
        cmaxr[j] = v;
        if (lane == 0) bcmax[j * 8 + w] = v;
      }
      mw = fmaxf(mw, cmaxr[j]);
    }
    if (lane == 0) mred[par][w] = mw;
    __syncthreads();                       // B1
    if (tid == 0) cand[1 - par] = 0x7FFFFFFF;   // reset for iter t+1

    float M = fmaxf(fmaxf(fmaxf(mred[par][0], mred[par][1]),
                          fmaxf(mred[par][2], mred[par][3])),
                    fmaxf(fmaxf(mred[par][4], mred[par][5]),
                          fmaxf(mred[par][6], mred[par][7])));
    if (mw == M) {                          // uniform; usually one wave
#pragma unroll
      for (int j = 0; j < 16; j++) {
        if (cmaxr[j] == M) {                // uniform per slot
          if (dd[j] == M)                   // divergent: candidate lanes
            atomicMin(&cand[par], (oi[j] << 13) | (j * 512 + tid));
        }
      }
    }
    __syncthreads();                       // B2
    int pk = cand[par];
    int srt = pk & 8191;
    int nxt = pk >> 13;
    qx = ssx[srt]; qy = ssy[srt]; qz = ssz[srt];
    if (tid == 0) {
      out_inds[b * NPOINT + t] = (float)nxt;
      out_xyz[((size_t)b * NPOINT + t) * 3 + 0] = qx;
      out_xyz[((size_t)b * NPOINT + t) * 3 + 1] = qy;
      out_xyz[((size_t)b * NPOINT + t) * 3 + 2] = qz;
    }
  }
}

// ---------------- prep: pad W0 rows to 68, precompute scale/shift ------------
__global__ __launch_bounds__(256) void prep_kernel(
    const float* __restrict__ W0, const float* __restrict__ g0,
    const float* __restrict__ b0, const float* __restrict__ m0,
    const float* __restrict__ v0, const float* __restrict__ g1,
    const float* __restrict__ b1, const float* __restrict__ m1,
    const float* __restrict__ v1, const float* __restrict__ g2,
    const float* __restrict__ b2, const float* __restrict__ m2,
    const float* __restrict__ v2, float* __restrict__ wsp) {
  const int tid = threadIdx.x;
  for (int idx = tid; idx < 64 * K0P; idx += 256) {
    int o = idx / K0P, i = idx - o * K0P;
    wsp[idx] = (i < K0) ? W0[o * K0 + i] : 0.f;
  }
  float* s = wsp + 64 * K0P;
  if (tid < 64) {
    float t0 = g0[tid] / sqrtf(v0[tid] + 1e-5f);
    s[tid] = t0; s[64 + tid] = b0[tid] - m0[tid] * t0;
    float t1 = g1[tid] / sqrtf(v1[tid] + 1e-5f);
    s[128 + tid] = t1; s[192 + tid] = b1[tid] - m1[tid] * t1;
  }
  if (tid < 128) {
    float t2 = g2[tid] / sqrtf(v2[tid] + 1e-5f);
    s[256 + tid] = t2; s[384 + tid] = b2[tid] - m2[tid] * t2;
  }
}

// ---------------- feature transpose: [b][c][n] -> [b][n][c] ------------------
__global__ __launch_bounds__(256) void transpose_kernel(const float* __restrict__ feat,
                                                        float* __restrict__ featT) {
  __shared__ float tile[64][65];
  const int bt = blockIdx.x;          // b*128 + ntile
  const int b = bt >> 7, nt = bt & 127;
  const int tid = threadIdx.x;
  const int r0 = tid >> 6, cc = tid & 63;
  const float* fb = feat + (size_t)b * 64 * NPTS + (size_t)nt * 64;
#pragma unroll
  for (int r = r0; r < 64; r += 4)
    tile[r][cc] = fb[(size_t)r * NPTS + cc];
  __syncthreads();
  float* ob = featT + ((size_t)b * NPTS + (size_t)nt * 64) * 64;
#pragma unroll
  for (int n = r0; n < 64; n += 4)
    ob[(size_t)n * 64 + cc] = tile[cc][n];
}

// ---------------- ball query: one wave per query point -----------------------
__global__ __launch_bounds__(256) void ballq_kernel(const float* __restrict__ xyz,
                                                    const float* __restrict__ new_xyz,
                                                    int* __restrict__ ball) {
  const int lane = threadIdx.x & 63;
  const int q = blockIdx.x * 4 + (threadIdx.x >> 6);
  const int b = q >> 11;
  const float RR = (float)(0.4 * 0.4);
  const float cx = new_xyz[(size_t)q * 3 + 0];
  const float cy = new_xyz[(size_t)q * 3 + 1];
  const float cz = new_xyz[(size_t)q * 3 + 2];
  const float* xb = xyz + (size_t)b * NPTS * 3;
  int cnt = 0, firsti = -1;
  for (int base = 0; base < NPTS; base += 64) {
    int i = base + lane;
    float xx = xb[i * 3 + 0], yy = xb[i * 3 + 1], zz = xb[i * 3 + 2];
    float d2 = d2e(xx, yy, zz, cx, cy, cz);
    bool m = d2 < RR;
    unsigned long long mask = __ballot(m);
    if (mask) {
      if (firsti < 0) firsti = base + (__ffsll((unsigned long long)mask) - 1);
      int pos = cnt + (int)__popcll(mask & ((1ull << lane) - 1ull));
      if (m && pos < NSAMPLE) ball[(size_t)q * NSAMPLE + pos] = i;
      cnt += (int)__popcll(mask);
      if (cnt >= NSAMPLE) break;
    }
  }
  for (int s = cnt + lane; s < NSAMPLE; s += 64)
    ball[(size_t)q * NSAMPLE + s] = firsti;
}

// ---------------- grouped MLP (3 layers) + max-pool: one wave per point ------
// lane == sample. Activations staged per-wave in LDS [64ch][64lane] so o-loops
// stay dynamic (small code, no spills). Weight rows are wave-uniform float4.
__global__ __launch_bounds__(256) void mlp_kernel(
    const float* __restrict__ xyz, const float* __restrict__ featT,
    const int* __restrict__ ball, const float* __restrict__ new_xyz,
    const float* __restrict__ W1, const float* __restrict__ W2,
    const float* __restrict__ wsp, float* __restrict__ out_feat) {
  __shared__ float yb[4][64 * 64];
  const int tid = threadIdx.x;
  const int lane = tid & 63, wid = tid >> 6;
  const int q = blockIdx.x * 4 + wid;
  const int b = q >> 11, p = q & 2047;

  const float* W0p = wsp;
  const float* sc0 = wsp + 64 * K0P;
  const float* sh0 = sc0 + 64;
  const float* sc1 = sc0 + 128;
  const float* sh1 = sc0 + 192;
  const float* sc2 = sc0 + 256;
  const float* sh2 = sc0 + 384;

  const float cx = new_xyz[(size_t)q * 3 + 0];
  const float cy = new_xyz[(size_t)q * 3 + 1];
  const float cz = new_xyz[(size_t)q * 3 + 2];
  const int sidx = ball[(size_t)q * NSAMPLE + lane];
  const float* xb = xyz + (size_t)b * NPTS * 3;

  float x[K0P];
  x[0] = xb[(size_t)sidx * 3 + 0] - cx;
  x[1] = xb[(size_t)sidx * 3 + 1] - cy;
  x[2] = xb[(size_t)sidx * 3 + 2] - cz;
  const float4* row =
      (const float4*)(featT + ((size_t)b * NPTS + (size_t)sidx) * 64);
#pragma unroll
  for (int i = 0; i < 16; i++) {
    float4 v = row[i];
    x[3 + 4 * i + 0] = v.x; x[3 + 4 * i + 1] = v.y;
    x[3 + 4 * i + 2] = v.z; x[3 + 4 * i + 3] = v.w;
  }
  x[67] = 0.f;

  float* Y = yb[wid];
  // ---- layer 0: 67(pad 68) -> 64
#pragma unroll 2
  for (int o = 0; o < 64; o++) {
    const float4* wr = (const float4*)(W0p + o * K0P);
    float a0 = 0.f, a1 = 0.f, a2 = 0.f, a3 = 0.f;
#pragma unroll
    for (int i = 0; i < 17; i++) {
      float4 wv = wr[i];
      a0 = fmaf(wv.x, x[4 * i + 0], a0);
      a1 = fmaf(wv.y, x[4 * i + 1], a1);
      a2 = fmaf(wv.z, x[4 * i + 2], a2);
      a3 = fmaf(wv.w, x[4 * i + 3], a3);
    }
    float acc = (a0 + a1) + (a2 + a3);
    Y[o * 64 + lane] = fmaxf(fmaf(acc, sc0[o], sh0[o]), 0.f);
  }
  float x2[64];
#pragma unroll
  for (int i = 0; i < 64; i++) x2[i] = Y[i * 64 + lane];
  // ---- layer 1: 64 -> 64
#pragma unroll 2
  for (int o = 0; o < 64; o++) {
    const float4* wr = (const float4*)(W1 + o * 64);
    float a0 = 0.f, a1 = 0.f, a2 = 0.f, a3 = 0.f;
#pragma unroll
    for (int i = 0; i < 16; i++) {
      float4 wv = wr[i];
      a0 = fmaf(wv.x, x2[4 * i + 0], a0);
      a1 = fmaf(wv.y, x2[4 * i + 1], a1);
      a2 = fmaf(wv.z, x2[4 * i + 2], a2);
      a3 = fmaf(wv.w, x2[4 * i + 3], a3);
    }
    float acc = (a0 + a1) + (a2 + a3);
    Y[o * 64 + lane] = fmaxf(fmaf(acc, sc1[o], sh1[o]), 0.f);
  }
  float x3[64];
#pragma unroll
  for (int i = 0; i < 64; i++) x3[i] = Y[i * 64 + lane];
  // ---- layer 2: 64 -> 128, fused max over samples (lanes)
  float* ob = out_feat + (size_t)b * C2 * NPOINT + p;
#pragma unroll 2
  for (int o = 0; o < C2; o++) {
    const float4* wr = (const float4*)(W2 + o * 64);
    float a0 = 0.f, a1 = 0.f, a2 = 0.f, a3 = 0.f;
#pragma unroll
    for (int i = 0; i < 16; i++) {
      float4 wv = wr[i];
      a0 = fmaf(wv.x, x3[4 * i + 0], a0);
      a1 = fmaf(wv.y, x3[4 * i + 1], a1);
      a2 = fmaf(wv.z, x3[4 * i + 2], a2);
      a3 = fmaf(wv.w, x3[4 * i + 3], a3);
    }
    float acc = (a0 + a1) + (a2 + a3);
    float y = fmaxf(fmaf(acc, sc2[o], sh2[o]), 0.f);
#pragma unroll
    for (int m = 1; m < 64; m <<= 1) y = fmaxf(y, __shfl_xor(y, m, 64));
    if (lane == 0) ob[(size_t)o * NPOINT] = y;
  }
}

extern "C" void kernel_launch(void* const* d_in, const int* in_sizes, int n_in,
                              void* d_out, int out_size, void* d_ws, size_t ws_size,
                              hipStream_t stream) {
  const float* xyz  = (const float*)d_in[0];
  const float* feat = (const float*)d_in[1];
  const float* W0 = (const float*)d_in[2];
  const float* g0 = (const float*)d_in[3];
  const float* b0 = (const float*)d_in[4];
  const float* m0 = (const float*)d_in[5];
  const float* v0 = (const float*)d_in[6];
  const float* W1 = (const float*)d_in[7];
  const float* g1 = (const float*)d_in[8];
  const float* b1 = (const float*)d_in[9];
  const float* m1 = (const float*)d_in[10];
  const float* v1 = (const float*)d_in[11];
  const float* W2 = (const float*)d_in[12];
  const float* g2 = (const float*)d_in[13];
  const float* b2 = (const float*)d_in[14];
  const float* m2 = (const float*)d_in[15];
  const float* v2 = (const float*)d_in[16];

  float* out = (float*)d_out;
  float* out_xyz  = out;                         // (8,2048,3)   = 49152
  float* out_feat = out + 49152;                 // (8,128,2048) = 2097152
  float* out_inds = out + 49152 + 2097152;       // (8,2048)     = 16384

  int*   ball  = (int*)d_ws;                                           // 4 MiB
  float* featT = (float*)((char*)d_ws + (size_t)BATCH * NPOINT * NSAMPLE * 4);
  float* wsp   = (float*)((char*)d_ws + 20971520);                     // ~20 KiB

  hipLaunchKernelGGL(prep_kernel, dim3(1), dim3(256), 0, stream,
                     W0, g0, b0, m0, v0, g1, b1, m1, v1, g2, b2, m2, v2, wsp);
  hipLaunchKernelGGL(transpose_kernel, dim3(BATCH * (NPTS / 64)), dim3(256), 0, stream,
                     feat, featT);
  hipLaunchKernelGGL(fps_kernel, dim3(BATCH), dim3(512), 0, stream,
                     xyz, out_xyz, out_inds);
  hipLaunchKernelGGL(ballq_kernel, dim3((BATCH * NPOINT) / 4), dim3(256), 0, stream,
                     xyz, out_xyz, ball);
  hipLaunchKernelGGL(mlp_kernel, dim3((BATCH * NPOINT) / 4), dim3(256), 0, stream,
                     xyz, featT, ball, out_xyz, W1, W2, wsp, out_feat);
}

// Round 4
// 4581.817 us; speedup vs baseline: 1.3016x; 1.3016x over previous
//
#include <hip/hip_runtime.h>
#include <cstdint>
#include <cstddef>

#define BATCH   8
#define NPTS    8192
#define NPOINT  2048
#define NSAMPLE 64
#define K0      67      // 3 + 64 input channels
#define K0P     68      // padded row stride (16B-aligned rows)
#define C2      128

// Exact-order squared distance, matching XLA/numpy: ((dx*dx + dy*dy) + dz*dz),
// separate mul/add (no FMA contraction), round-to-nearest f32.
__device__ __forceinline__ float d2e(float ax, float ay, float az,
                                     float bx, float by, float bz) {
#pragma clang fp contract(off)
  float dx = ax - bx;
  float dy = ay - by;
  float dz = az - bz;
  float t0 = dx * dx;
  float t1 = dy * dy;
  float t2 = dz * dz;
  return (t0 + t1) + t2;
}

__device__ __forceinline__ float wave_fmax(float v) {
#pragma unroll
  for (int m = 1; m < 64; m <<= 1) v = fmaxf(v, __shfl_xor(v, m, 64));
  return v;
}

// key = (~bits(dd) << 32) | origIdx  -> min key == (max value, min index)
__device__ __forceinline__ unsigned long long packkey(float d, int oi) {
  unsigned v = ~__float_as_uint(d);
  return ((unsigned long long)v << 32) | (unsigned)oi;
}

__device__ __forceinline__ int quant4(float v) {
  return (v < -0.6745f) ? 0 : (v < 0.f) ? 1 : (v < 0.6745f) ? 2 : 3;
}

// ---------------- FPS: bucket-pruned serial argmax ---------------------------
// One block/batch. Points counting-sorted into 128 spatially-tight chunks of
// 64 ("buckets", serpentine cell order). Wave w owns buckets w*16+j (j=0..15),
// lane l owns sorted slot bucket*64+l. Prune test uses the GLOBAL current max
// (gmax, from the winner key) as a uniform upper bound: a bucket can be
// skipped iff dist(q, c_b) > r_b + sqrt(gmax) (with slack >> f32 rounding),
// which provably cannot change any dd -> dd stays bit-exact vs reference.
__global__ __launch_bounds__(512) void fps_kernel(const float* __restrict__ xyz,
                                                  float* __restrict__ out_xyz,
                                                  float* __restrict__ out_inds) {
  const int b = blockIdx.x;
  const int tid = threadIdx.x;
  const int lane = tid & 63, w = tid >> 6;

  __shared__ float sx[NPTS], sy[NPTS], sz[NPTS];   // ORIGINAL order (q lookup)
  __shared__ int   soi[NPTS];                      // sorted slot -> orig idx
  __shared__ float4 bgeo[128];                     // cx,cy,cz,rb  [w*16+j]
  __shared__ unsigned long long wred[2][8];
  __shared__ int hist[64], cbase[64], ccnt[64];

  const float* xb = xyz + (size_t)b * NPTS * 3;

  if (tid < 64) { hist[tid] = 0; ccnt[tid] = 0; }
  __syncthreads();

  // --- stage coords (original order) + histogram of serpentine cells
  int lc[16];
#pragma unroll
  for (int k = 0; k < 16; k++) {
    int i = tid + k * 512;
    float x = xb[i * 3 + 0], y = xb[i * 3 + 1], z = xb[i * 3 + 2];
    sx[i] = x; sy[i] = y; sz[i] = z;
    int qx_ = quant4(x), qy_ = quant4(y), qz_ = quant4(z);
    int yy = (qx_ & 1) ? 3 - qy_ : qy_;
    int zz = ((qx_ ^ yy) & 1) ? 3 - qz_ : qz_;
    int cell = qx_ * 16 + yy * 4 + zz;
    lc[k] = cell;
    atomicAdd(&hist[cell], 1);
  }
  __syncthreads();
  if (tid == 0) {
    int s = 0;
    for (int c = 0; c < 64; c++) { cbase[c] = s; s += hist[c]; }
  }
  __syncthreads();
#pragma unroll
  for (int k = 0; k < 16; k++) {
    int pos = cbase[lc[k]] + atomicAdd(&ccnt[lc[k]], 1);
    soi[pos] = tid + k * 512;
  }
  __syncthreads();

  const float q0x = sx[0], q0y = sy[0], q0z = sz[0];

  // --- gather owned points to regs, init dd/keys, bucket geometry
  float px[16], py[16], pz[16], dd[16];
  int oi[16];
  unsigned long long k64[16];
#pragma unroll
  for (int j = 0; j < 16; j++) {
    int s = (w * 16 + j) * 64 + lane;
    int o = soi[s];
    oi[j] = o;
    px[j] = sx[o]; py[j] = sy[o]; pz[j] = sz[o];
    dd[j] = d2e(px[j], py[j], pz[j], q0x, q0y, q0z);
    k64[j] = packkey(dd[j], o);
    float xhi = wave_fmax(px[j]), xlo = -wave_fmax(-px[j]);
    float yhi = wave_fmax(py[j]), ylo = -wave_fmax(-py[j]);
    float zhi = wave_fmax(pz[j]), zlo = -wave_fmax(-pz[j]);
    float cx = 0.5f * (xlo + xhi), cy = 0.5f * (ylo + yhi), cz = 0.5f * (zlo + zhi);
    float r2 = wave_fmax(d2e(px[j], py[j], pz[j], cx, cy, cz));
    float rb = sqrtf(r2) * 1.0002f + 1e-6f;        // certified over-estimate
    if (lane == 0) bgeo[w * 16 + j] = make_float4(cx, cy, cz, rb);
  }
  if (tid == 0) {
    out_inds[b * NPOINT] = 0.f;
    out_xyz[(size_t)b * NPOINT * 3 + 0] = q0x;
    out_xyz[(size_t)b * NPOINT * 3 + 1] = q0y;
    out_xyz[(size_t)b * NPOINT * 3 + 2] = q0z;
  }

  // --- initial wave candidate
  unsigned long long bk = k64[0];
#pragma unroll
  for (int j = 1; j < 16; j++) bk = (k64[j] < bk) ? k64[j] : bk;
#pragma unroll
  for (int m = 1; m < 64; m <<= 1) {
    unsigned long long o = __shfl_xor((unsigned long long)bk, m, 64);
    if (o < bk) bk = o;
  }
  if (lane == 0) wred[0][w] = bk;
  __syncthreads();

  for (int t = 1; t < NPOINT; ++t) {
    // --- global winner = min of 8 wave keys (broadcast reads)
    unsigned long long g0 = wred[(t - 1) & 1][0], g1 = wred[(t - 1) & 1][1];
    unsigned long long g2 = wred[(t - 1) & 1][2], g3 = wred[(t - 1) & 1][3];
    unsigned long long g4 = wred[(t - 1) & 1][4], g5 = wred[(t - 1) & 1][5];
    unsigned long long g6 = wred[(t - 1) & 1][6], g7 = wred[(t - 1) & 1][7];
    g0 = (g1 < g0) ? g1 : g0; g2 = (g3 < g2) ? g3 : g2;
    g4 = (g5 < g4) ? g5 : g4; g6 = (g7 < g6) ? g7 : g6;
    g0 = (g2 < g0) ? g2 : g0; g4 = (g6 < g4) ? g6 : g4;
    g0 = (g4 < g0) ? g4 : g0;
    const int nxt = (int)(g0 & 0xFFFFFFFFu);
    const float gmax = __uint_as_float(~(unsigned)(g0 >> 32));
    const float qx = sx[nxt], qy = sy[nxt], qz = sz[nxt];
    if (tid == 0) {
      out_inds[b * NPOINT + t] = (float)nxt;
      out_xyz[((size_t)b * NPOINT + t) * 3 + 0] = qx;
      out_xyz[((size_t)b * NPOINT + t) * 3 + 1] = qy;
      out_xyz[((size_t)b * NPOINT + t) * 3 + 2] = qz;
    }

    // --- prune check: lane jj tests bucket w*16+jj against uniform bound
    const float sg = sqrtf(gmax);
    const int jj = lane & 15;
    float4 g = bgeo[w * 16 + jj];
    float d2c = d2e(qx, qy, qz, g.x, g.y, g.z);
    float T = (g.w + sg) * 1.0005f + 1e-6f;
    bool dirty = !(d2c > T * T);
    unsigned dmask = (unsigned)__ballot(dirty) & 0xFFFFu;

    if (dmask) {
      // --- update dirty buckets (wave-uniform branches, static j)
#pragma unroll
      for (int j = 0; j < 16; j++) {
        if (dmask & (1u << j)) {
          float nd = fminf(dd[j], d2e(px[j], py[j], pz[j], qx, qy, qz));
          dd[j] = nd;
          k64[j] = packkey(nd, oi[j]);
        }
      }
      // --- rescan + wave reduce
      bk = k64[0];
#pragma unroll
      for (int j = 1; j < 16; j++) bk = (k64[j] < bk) ? k64[j] : bk;
#pragma unroll
      for (int m = 1; m < 64; m <<= 1) {
        unsigned long long o = __shfl_xor((unsigned long long)bk, m, 64);
        if (o < bk) bk = o;
      }
    }
    if (lane == 0) wred[t & 1][w] = bk;
    __syncthreads();
  }
}

// ---------------- prep: pad W0 rows to 68, precompute scale/shift ------------
__global__ __launch_bounds__(256) void prep_kernel(
    const float* __restrict__ W0, const float* __restrict__ g0,
    const float* __restrict__ b0, const float* __restrict__ m0,
    const float* __restrict__ v0, const float* __restrict__ g1,
    const float* __restrict__ b1, const float* __restrict__ m1,
    const float* __restrict__ v1, const float* __restrict__ g2,
    const float* __restrict__ b2, const float* __restrict__ m2,
    const float* __restrict__ v2, float* __restrict__ wsp) {
  const int tid = threadIdx.x;
  for (int idx = tid; idx < 64 * K0P; idx += 256) {
    int o = idx / K0P, i = idx - o * K0P;
    wsp[idx] = (i < K0) ? W0[o * K0 + i] : 0.f;
  }
  float* s = wsp + 64 * K0P;
  if (tid < 64) {
    float t0 = g0[tid] / sqrtf(v0[tid] + 1e-5f);
    s[tid] = t0; s[64 + tid] = b0[tid] - m0[tid] * t0;
    float t1 = g1[tid] / sqrtf(v1[tid] + 1e-5f);
    s[128 + tid] = t1; s[192 + tid] = b1[tid] - m1[tid] * t1;
  }
  if (tid < 128) {
    float t2 = g2[tid] / sqrtf(v2[tid] + 1e-5f);
    s[256 + tid] = t2; s[384 + tid] = b2[tid] - m2[tid] * t2;
  }
}

// ---------------- feature transpose: [b][c][n] -> [b][n][c] ------------------
__global__ __launch_bounds__(256) void transpose_kernel(const float* __restrict__ feat,
                                                        float* __restrict__ featT) {
  __shared__ float tile[64][65];
  const int bt = blockIdx.x;          // b*128 + ntile
  const int b = bt >> 7, nt = bt & 127;
  const int tid = threadIdx.x;
  const int r0 = tid >> 6, cc = tid & 63;
  const float* fb = feat + (size_t)b * 64 * NPTS + (size_t)nt * 64;
#pragma unroll
  for (int r = r0; r < 64; r += 4)
    tile[r][cc] = fb[(size_t)r * NPTS + cc];
  __syncthreads();
  float* ob = featT + ((size_t)b * NPTS + (size_t)nt * 64) * 64;
#pragma unroll
  for (int n = r0; n < 64; n += 4)
    ob[(size_t)n * 64 + cc] = tile[cc][n];
}

// ---------------- ball query: one wave per query point -----------------------
__global__ __launch_bounds__(256) void ballq_kernel(const float* __restrict__ xyz,
                                                    const float* __restrict__ new_xyz,
                                                    int* __restrict__ ball) {
  const int lane = threadIdx.x & 63;
  const int q = blockIdx.x * 4 + (threadIdx.x >> 6);
  const int b = q >> 11;
  const float RR = (float)(0.4 * 0.4);
  const float cx = new_xyz[(size_t)q * 3 + 0];
  const float cy = new_xyz[(size_t)q * 3 + 1];
  const float cz = new_xyz[(size_t)q * 3 + 2];
  const float* xb = xyz + (size_t)b * NPTS * 3;
  int cnt = 0, firsti = -1;
  for (int base = 0; base < NPTS; base += 64) {
    int i = base + lane;
    float xx = xb[i * 3 + 0], yy = xb[i * 3 + 1], zz = xb[i * 3 + 2];
    float d2 = d2e(xx, yy, zz, cx, cy, cz);
    bool m = d2 < RR;
    unsigned long long mask = __ballot(m);
    if (mask) {
      if (firsti < 0) firsti = base + (__ffsll((unsigned long long)mask) - 1);
      int pos = cnt + (int)__popcll(mask & ((1ull << lane) - 1ull));
      if (m && pos < NSAMPLE) ball[(size_t)q * NSAMPLE + pos] = i;
      cnt += (int)__popcll(mask);
      if (cnt >= NSAMPLE) break;
    }
  }
  for (int s = cnt + lane; s < NSAMPLE; s += 64)
    ball[(size_t)q * NSAMPLE + s] = firsti;
}

// ---------------- grouped MLP (3 layers) + max-pool --------------------------
// lane == sample; weights staged in LDS once per block; 16 queries per block
// (4 per wave) amortize the staging. L0/L1 fully unrolled (register
// activations, static indexing); L2 dynamic (output consumed immediately).
__global__ __launch_bounds__(256) void mlp_kernel(
    const float* __restrict__ xyz, const float* __restrict__ featT,
    const int* __restrict__ ball, const float* __restrict__ new_xyz,
    const float* __restrict__ W1, const float* __restrict__ W2,
    const float* __restrict__ wsp, float* __restrict__ out_feat) {
  __shared__ float sw[64 * K0P + 64 * 64 + 128 * 64];   // 16640 f32 = 66.5 KB
  __shared__ float sc[512];
  const int tid = threadIdx.x;
  const int lane = tid & 63, wid = tid >> 6;

  for (int i = tid; i < 64 * K0P; i += 256) sw[i] = wsp[i];
  for (int i = tid; i < 64 * 64; i += 256) sw[64 * K0P + i] = W1[i];
  for (int i = tid; i < 128 * 64; i += 256) sw[64 * K0P + 4096 + i] = W2[i];
  for (int i = tid; i < 512; i += 256) sc[i] = wsp[64 * K0P + i];
  __syncthreads();

  const float* sc0 = sc;        const float* sh0 = sc + 64;
  const float* sc1 = sc + 128;  const float* sh1 = sc + 192;
  const float* sc2 = sc + 256;  const float* sh2 = sc + 384;

  for (int qi = 0; qi < 4; qi++) {
    const int q = blockIdx.x * 16 + qi * 4 + wid;
    const int b = q >> 11, p = q & 2047;

    const float cx = new_xyz[(size_t)q * 3 + 0];
    const float cy = new_xyz[(size_t)q * 3 + 1];
    const float cz = new_xyz[(size_t)q * 3 + 2];
    const int sidx = ball[(size_t)q * NSAMPLE + lane];
    const float* xb = xyz + (size_t)b * NPTS * 3;

    float x[K0P];
    x[0] = xb[(size_t)sidx * 3 + 0] - cx;
    x[1] = xb[(size_t)sidx * 3 + 1] - cy;
    x[2] = xb[(size_t)sidx * 3 + 2] - cz;
    const float4* row =
        (const float4*)(featT + ((size_t)b * NPTS + (size_t)sidx) * 64);
#pragma unroll
    for (int i = 0; i < 16; i++) {
      float4 v = row[i];
      x[3 + 4 * i + 0] = v.x; x[3 + 4 * i + 1] = v.y;
      x[3 + 4 * i + 2] = v.z; x[3 + 4 * i + 3] = v.w;
    }
    x[67] = 0.f;

    // ---- layer 0: 67(pad 68) -> 64  (full unroll, LDS weights broadcast)
    float y0r[64];
#pragma unroll
    for (int o = 0; o < 64; o++) {
      const float4* wr = (const float4*)(sw + o * K0P);
      float a0 = 0.f, a1 = 0.f, a2 = 0.f, a3 = 0.f;
#pragma unroll
      for (int i = 0; i < 17; i++) {
        float4 wv = wr[i];
        a0 = fmaf(wv.x, x[4 * i + 0], a0);
        a1 = fmaf(wv.y, x[4 * i + 1], a1);
        a2 = fmaf(wv.z, x[4 * i + 2], a2);
        a3 = fmaf(wv.w, x[4 * i + 3], a3);
      }
      float acc = (a0 + a1) + (a2 + a3);
      y0r[o] = fmaxf(fmaf(acc, sc0[o], sh0[o]), 0.f);
    }
    // ---- layer 1: 64 -> 64
    float y1r[64];
#pragma unroll
    for (int o = 0; o < 64; o++) {
      const float4* wr = (const float4*)(sw + 64 * K0P + o * 64);
      float a0 = 0.f, a1 = 0.f, a2 = 0.f, a3 = 0.f;
#pragma unroll
      for (int i = 0; i < 16; i++) {
        float4 wv = wr[i];
        a0 = fmaf(wv.x, y0r[4 * i + 0], a0);
        a1 = fmaf(wv.y, y0r[4 * i + 1], a1);
        a2 = fmaf(wv.z, y0r[4 * i + 2], a2);
        a3 = fmaf(wv.w, y0r[4 * i + 3], a3);
      }
      float acc = (a0 + a1) + (a2 + a3);
      y1r[o] = fmaxf(fmaf(acc, sc1[o], sh1[o]), 0.f);
    }
    // ---- layer 2: 64 -> 128, fused max over samples (lanes)
    float* ob = out_feat + (size_t)b * C2 * NPOINT + p;
#pragma unroll 2
    for (int o = 0; o < C2; o++) {
      const float4* wr = (const float4*)(sw + 64 * K0P + 4096 + o * 64);
      float a0 = 0.f, a1 = 0.f, a2 = 0.f, a3 = 0.f;
#pragma unroll
      for (int i = 0; i < 16; i++) {
        float4 wv = wr[i];
        a0 = fmaf(wv.x, y1r[4 * i + 0], a0);
        a1 = fmaf(wv.y, y1r[4 * i + 1], a1);
        a2 = fmaf(wv.z, y1r[4 * i + 2], a2);
        a3 = fmaf(wv.w, y1r[4 * i + 3], a3);
      }
      float acc = (a0 + a1) + (a2 + a3);
      float y = fmaxf(fmaf(acc, sc2[o], sh2[o]), 0.f);
#pragma unroll
      for (int m = 1; m < 64; m <<= 1) y = fmaxf(y, __shfl_xor(y, m, 64));
      if (lane == 0) ob[(size_t)o * NPOINT] = y;
    }
  }
}

extern "C" void kernel_launch(void* const* d_in, const int* in_sizes, int n_in,
                              void* d_out, int out_size, void* d_ws, size_t ws_size,
                              hipStream_t stream) {
  const float* xyz  = (const float*)d_in[0];
  const float* feat = (const float*)d_in[1];
  const float* W0 = (const float*)d_in[2];
  const float* g0 = (const float*)d_in[3];
  const float* b0 = (const float*)d_in[4];
  const float* m0 = (const float*)d_in[5];
  const float* v0 = (const float*)d_in[6];
  const float* W1 = (const float*)d_in[7];
  const float* g1 = (const float*)d_in[8];
  const float* b1 = (const float*)d_in[9];
  const float* m1 = (const float*)d_in[10];
  const float* v1 = (const float*)d_in[11];
  const float* W2 = (const float*)d_in[12];
  const float* g2 = (const float*)d_in[13];
  const float* b2 = (const float*)d_in[14];
  const float* m2 = (const float*)d_in[15];
  const float* v2 = (const float*)d_in[16];

  float* out = (float*)d_out;
  float* out_xyz  = out;                         // (8,2048,3)   = 49152
  float* out_feat = out + 49152;                 // (8,128,2048) = 2097152
  float* out_inds = out + 49152 + 2097152;       // (8,2048)     = 16384

  int*   ball  = (int*)d_ws;                                           // 4 MiB
  float* featT = (float*)((char*)d_ws + (size_t)BATCH * NPOINT * NSAMPLE * 4);
  float* wsp   = (float*)((char*)d_ws + 20971520);                     // ~20 KiB

  hipLaunchKernelGGL(prep_kernel, dim3(1), dim3(256), 0, stream,
                     W0, g0, b0, m0, v0, g1, b1, m1, v1, g2, b2, m2, v2, wsp);
  hipLaunchKernelGGL(transpose_kernel, dim3(BATCH * (NPTS / 64)), dim3(256), 0, stream,
                     feat, featT);
  hipLaunchKernelGGL(fps_kernel, dim3(BATCH), dim3(512), 0, stream,
                     xyz, out_xyz, out_inds);
  hipLaunchKernelGGL(ballq_kernel, dim3((BATCH * NPOINT) / 4), dim3(256), 0, stream,
                     xyz, out_xyz, ball);
  hipLaunchKernelGGL(mlp_kernel, dim3(BATCH * NPOINT / 16), dim3(256), 0, stream,
                     xyz, featT, ball, out_xyz, W1, W2, wsp, out_feat);
}

// Round 5
// 4232.306 us; speedup vs baseline: 1.4091x; 1.0826x over previous
//
#include <hip/hip_runtime.h>
#include <cstdint>
#include <cstddef>

#define BATCH   8
#define NPTS    8192
#define NPOINT  2048
#define NSAMPLE 64
#define K0      67      // 3 + 64 input channels
#define C2      128

// Exact-order squared distance, matching XLA/numpy: ((dx*dx + dy*dy) + dz*dz),
// separate mul/add (no FMA contraction), round-to-nearest f32.
__device__ __forceinline__ float d2e(float ax, float ay, float az,
                                     float bx, float by, float bz) {
#pragma clang fp contract(off)
  float dx = ax - bx;
  float dy = ay - by;
  float dz = az - bz;
  float t0 = dx * dx;
  float t1 = dy * dy;
  float t2 = dz * dz;
  return (t0 + t1) + t2;
}

__device__ __forceinline__ float wave_fmax(float v) {
#pragma unroll
  for (int m = 1; m < 64; m <<= 1) v = fmaxf(v, __shfl_xor(v, m, 64));
  return v;
}

// octile quantile of N(0,1): boundaries Phi^-1(k/8)
__device__ __forceinline__ int quant8(float v) {
  int q = 0;
  q += (v >= -1.1503f); q += (v >= -0.6745f); q += (v >= -0.3186f);
  q += (v >= 0.f);
  q += (v >= 0.3186f);  q += (v >= 0.6745f);  q += (v >= 1.1503f);
  return q;
}

// ---------------- FPS: bucket-pruned serial argmax ---------------------------
// One block/batch. Points counting-sorted into 128 chunks of 64 ("buckets")
// by serpentine-ordered 8x8x8 octile cells. Wave w owns buckets w*16+j, lane l
// owns sorted slot bucket*64+l. Prune: bucket skippable iff
// dist(q,c_b) > r_b + sqrt(gmax) (slack >> f32 rounding) -> dd stays bit-exact.
__global__ __launch_bounds__(512) void fps_kernel(const float* __restrict__ xyz,
                                                  float* __restrict__ out_xyz,
                                                  float* __restrict__ out_inds) {
  const int b = blockIdx.x;
  const int tid = threadIdx.x;
  const int lane = tid & 63, w = tid >> 6;

  __shared__ float sx[NPTS], sy[NPTS], sz[NPTS];   // ORIGINAL order (q lookup)
  __shared__ int   soi[NPTS];                      // sorted slot -> orig idx
  __shared__ float4 bgeo[128];                     // cx,cy,cz,rb  [w*16+j]
  __shared__ unsigned long long wred[2][8];
  __shared__ int hist[512], cbase[512], ccnt[512];
  __shared__ int wsum[8];

  const float* xb = xyz + (size_t)b * NPTS * 3;

  hist[tid] = 0; ccnt[tid] = 0;
  __syncthreads();

  // --- stage coords (original order) + histogram of serpentine octile cells
  int lc[16];
#pragma unroll
  for (int k = 0; k < 16; k++) {
    int i = tid + k * 512;
    float x = xb[i * 3 + 0], y = xb[i * 3 + 1], z = xb[i * 3 + 2];
    sx[i] = x; sy[i] = y; sz[i] = z;
    int qx_ = quant8(x), qy_ = quant8(y), qz_ = quant8(z);
    int yp = (qx_ & 1) ? 7 - qy_ : qy_;
    int zp = (yp & 1) ? 7 - qz_ : qz_;
    int cell = qx_ * 64 + yp * 8 + zp;
    lc[k] = cell;
    atomicAdd(&hist[cell], 1);
  }
  __syncthreads();
  // --- parallel exclusive prefix over 512 bins
  {
    int v = hist[tid];
    int incl = v;
#pragma unroll
    for (int off = 1; off < 64; off <<= 1) {
      int o = __shfl_up(incl, off, 64);
      if (lane >= off) incl += o;
    }
    if (lane == 63) wsum[w] = incl;
    __syncthreads();
    int base = 0;
#pragma unroll
    for (int k = 0; k < 8; k++) base += (k < w) ? wsum[k] : 0;
    cbase[tid] = base + incl - v;
    __syncthreads();
  }
#pragma unroll
  for (int k = 0; k < 16; k++) {
    int pos = cbase[lc[k]] + atomicAdd(&ccnt[lc[k]], 1);
    soi[pos] = tid + k * 512;
  }
  __syncthreads();

  const float q0x = sx[0], q0y = sy[0], q0z = sz[0];

  // --- gather owned points to regs, init dd, bucket geometry
  float px[16], py[16], pz[16], dd[16];
  int oi[16];
#pragma unroll
  for (int j = 0; j < 16; j++) {
    int s = (w * 16 + j) * 64 + lane;
    int o = soi[s];
    oi[j] = o;
    px[j] = sx[o]; py[j] = sy[o]; pz[j] = sz[o];
    dd[j] = d2e(px[j], py[j], pz[j], q0x, q0y, q0z);
    float xhi = wave_fmax(px[j]), xlo = -wave_fmax(-px[j]);
    float yhi = wave_fmax(py[j]), ylo = -wave_fmax(-py[j]);
    float zhi = wave_fmax(pz[j]), zlo = -wave_fmax(-pz[j]);
    float cx = 0.5f * (xlo + xhi), cy = 0.5f * (ylo + yhi), cz = 0.5f * (zlo + zhi);
    float r2 = wave_fmax(d2e(px[j], py[j], pz[j], cx, cy, cz));
    float rb = sqrtf(r2) * 1.0002f + 1e-6f;        // certified over-estimate
    if (lane == 0) bgeo[w * 16 + j] = make_float4(cx, cy, cz, rb);
  }
  if (tid == 0) {
    out_inds[b * NPOINT] = 0.f;
    out_xyz[(size_t)b * NPOINT * 3 + 0] = q0x;
    out_xyz[(size_t)b * NPOINT * 3 + 1] = q0y;
    out_xyz[(size_t)b * NPOINT * 3 + 2] = q0z;
  }

  // --- initial candidate: per-thread scan (exact first-index tie-break), then
  //     f32-max reduce + tie-resolving u32-min reduce
  unsigned long long bk;
  {
    float bv = dd[0]; int boi = oi[0];
#pragma unroll
    for (int j = 1; j < 16; j++) {
      bool better = (dd[j] > bv) || (dd[j] == bv && oi[j] < boi);
      bv = better ? dd[j] : bv; boi = better ? oi[j] : boi;
    }
    float vm = wave_fmax(bv);
    int ci = (bv == vm) ? boi : 0x7FFFFFFF;
#pragma unroll
    for (int m = 1; m < 64; m <<= 1) ci = min(ci, __shfl_xor(ci, m, 64));
    bk = ((unsigned long long)(~__float_as_uint(vm)) << 32) | (unsigned)ci;
  }
  if (lane == 0) wred[0][w] = bk;
  __syncthreads();

  for (int t = 1; t < NPOINT; ++t) {
    // --- global winner = min of 8 wave keys (broadcast reads)
    const int pp = (t - 1) & 1;
    unsigned long long g0 = wred[pp][0], g1 = wred[pp][1];
    unsigned long long g2 = wred[pp][2], g3 = wred[pp][3];
    unsigned long long g4 = wred[pp][4], g5 = wred[pp][5];
    unsigned long long g6 = wred[pp][6], g7 = wred[pp][7];
    g0 = (g1 < g0) ? g1 : g0; g2 = (g3 < g2) ? g3 : g2;
    g4 = (g5 < g4) ? g5 : g4; g6 = (g7 < g6) ? g7 : g6;
    g0 = (g2 < g0) ? g2 : g0; g4 = (g6 < g4) ? g6 : g4;
    g0 = (g4 < g0) ? g4 : g0;
    const int nxt = (int)(g0 & 0xFFFFFFFFu);
    const float gmax = __uint_as_float(~(unsigned)(g0 >> 32));
    const float qx = sx[nxt], qy = sy[nxt], qz = sz[nxt];
    if (tid == 0) {
      out_inds[b * NPOINT + t] = (float)nxt;
      out_xyz[((size_t)b * NPOINT + t) * 3 + 0] = qx;
      out_xyz[((size_t)b * NPOINT + t) * 3 + 1] = qy;
      out_xyz[((size_t)b * NPOINT + t) * 3 + 2] = qz;
    }

    // --- prune check: lane jj tests bucket w*16+jj against uniform bound
    const float sg = sqrtf(gmax);
    const int jj = lane & 15;
    float4 g = bgeo[w * 16 + jj];
    float d2c = d2e(qx, qy, qz, g.x, g.y, g.z);
    float T = (g.w + sg) * 1.0005f + 1e-6f;
    bool dirty = !(d2c > T * T);
    unsigned dmask = (unsigned)__ballot(dirty) & 0xFFFFu;

    if (dmask) {
#pragma unroll
      for (int j = 0; j < 16; j++) {
        if (dmask & (1u << j)) {
          dd[j] = fminf(dd[j], d2e(px[j], py[j], pz[j], qx, qy, qz));
        }
      }
      float bv = dd[0]; int boi = oi[0];
#pragma unroll
      for (int j = 1; j < 16; j++) {
        bool better = (dd[j] > bv) || (dd[j] == bv && oi[j] < boi);
        bv = better ? dd[j] : bv; boi = better ? oi[j] : boi;
      }
      float vm = wave_fmax(bv);
      int ci = (bv == vm) ? boi : 0x7FFFFFFF;
#pragma unroll
      for (int m = 1; m < 64; m <<= 1) ci = min(ci, __shfl_xor(ci, m, 64));
      bk = ((unsigned long long)(~__float_as_uint(vm)) << 32) | (unsigned)ci;
    }
    if (lane == 0) wred[t & 1][w] = bk;
    __syncthreads();
  }
}

// ---------------- prep: fold BN into per-channel consts ----------------------
// wsp floats: [0..255] A4[o]={sc0*W0x,sc0*W0y,sc0*W0z,sh0}; [256..319] sc1;
// [320..383] sh1; [384..511] sc2; [512..639] sh2; [640..703] sc0
__global__ __launch_bounds__(128) void prep_kernel(
    const float* __restrict__ W0, const float* __restrict__ g0,
    const float* __restrict__ b0, const float* __restrict__ m0,
    const float* __restrict__ v0, const float* __restrict__ g1,
    const float* __restrict__ b1, const float* __restrict__ m1,
    const float* __restrict__ v1, const float* __restrict__ g2,
    const float* __restrict__ b2, const float* __restrict__ m2,
    const float* __restrict__ v2, float* __restrict__ wsp) {
  const int tid = threadIdx.x;
  if (tid < 64) {
    float s0 = g0[tid] / sqrtf(v0[tid] + 1e-5f);
    wsp[4 * tid + 0] = s0 * W0[tid * K0 + 0];
    wsp[4 * tid + 1] = s0 * W0[tid * K0 + 1];
    wsp[4 * tid + 2] = s0 * W0[tid * K0 + 2];
    wsp[4 * tid + 3] = b0[tid] - m0[tid] * s0;
    wsp[640 + tid] = s0;
    float s1 = g1[tid] / sqrtf(v1[tid] + 1e-5f);
    wsp[256 + tid] = s1; wsp[320 + tid] = b1[tid] - m1[tid] * s1;
  }
  float s2 = g2[tid] / sqrtf(v2[tid] + 1e-5f);
  wsp[384 + tid] = s2; wsp[512 + tid] = b2[tid] - m2[tid] * s2;
}

// ---------------- zfeat: per-point L0 linear part ----------------------------
// szp[n][o] = sc0[o] * ( W0[o][0:3] . p_xyz + W0[o][3:67] . feat[:,n] )
// lane = output channel o; block = 64-point tile.
__global__ __launch_bounds__(256) void zfeat_kernel(const float* __restrict__ xyz,
                                                    const float* __restrict__ feat,
                                                    const float* __restrict__ W0,
                                                    const float* __restrict__ wsp,
                                                    float* __restrict__ szp) {
  __shared__ float ftile[64][64];   // [c][u] - reads are wave-uniform
  __shared__ float sxyz[192];
  const int bt = blockIdx.x;        // b*128 + nt
  const int b = bt >> 7, nt = bt & 127;
  const int tid = threadIdx.x;
  const int lane = tid & 63, w = tid >> 6;

  const float* fb = feat + (size_t)b * 64 * NPTS + (size_t)nt * 64;
#pragma unroll
  for (int r = w; r < 64; r += 4)
    ftile[r][lane] = fb[(size_t)r * NPTS + lane];
  if (tid < 192)
    sxyz[tid] = xyz[((size_t)b * NPTS + (size_t)nt * 64) * 3 + tid];

  // per-lane W0 row (channel = lane)
  float w0x = W0[lane * K0 + 0], w0y = W0[lane * K0 + 1], w0z = W0[lane * K0 + 2];
  float wf[64];
#pragma unroll
  for (int i = 0; i < 64; i++) wf[i] = W0[lane * K0 + 3 + i];
  const float s0 = wsp[640 + lane];
  __syncthreads();

  float* ob = szp + ((size_t)b * NPTS + (size_t)nt * 64) * 64;
  for (int u = w; u < 64; u += 4) {
    float acc = w0x * sxyz[u * 3 + 0] + w0y * sxyz[u * 3 + 1] + w0z * sxyz[u * 3 + 2];
#pragma unroll
    for (int i = 0; i < 64; i++) acc = fmaf(wf[i], ftile[i][u], acc);
    ob[(size_t)u * 64 + lane] = acc * s0;
  }
}

// ---------------- ball query: one wave per query point -----------------------
__global__ __launch_bounds__(256) void ballq_kernel(const float* __restrict__ xyz,
                                                    const float* __restrict__ new_xyz,
                                                    int* __restrict__ ball) {
  const int lane = threadIdx.x & 63;
  const int q = blockIdx.x * 4 + (threadIdx.x >> 6);
  const int b = q >> 11;
  const float RR = (float)(0.4 * 0.4);
  const float cx = new_xyz[(size_t)q * 3 + 0];
  const float cy = new_xyz[(size_t)q * 3 + 1];
  const float cz = new_xyz[(size_t)q * 3 + 2];
  const float* xb = xyz + (size_t)b * NPTS * 3;
  int cnt = 0, firsti = -1;
  for (int base = 0; base < NPTS; base += 64) {
    int i = base + lane;
    float xx = xb[i * 3 + 0], yy = xb[i * 3 + 1], zz = xb[i * 3 + 2];
    float d2 = d2e(xx, yy, zz, cx, cy, cz);
    bool m = d2 < RR;
    unsigned long long mask = __ballot(m);
    if (mask) {
      if (firsti < 0) firsti = base + (__ffsll((unsigned long long)mask) - 1);
      int pos = cnt + (int)__popcll(mask & ((1ull << lane) - 1ull));
      if (m && pos < NSAMPLE) ball[(size_t)q * NSAMPLE + pos] = i;
      cnt += (int)__popcll(mask);
      if (cnt >= NSAMPLE) break;
    }
  }
  for (int s = cnt + lane; s < NSAMPLE; s += 64)
    ball[(size_t)q * NSAMPLE + s] = firsti;
}

// ---------------- MLP L1/L2 + max-pool: lane = channel, loop samples ---------
// Weights in registers (lane o holds row o of W1, rows o and o+64 of W2).
// Activations pass through one 256B LDS row per wave (write y[lane], read as
// wave-uniform float4 broadcasts). Max-pool = running register max.
#define QPW 4
__global__ __launch_bounds__(256, 2) void mlp_kernel(
    const float* __restrict__ szp, const int* __restrict__ ball,
    const float* __restrict__ new_xyz, const float* __restrict__ W1,
    const float* __restrict__ W2, const float* __restrict__ wsp,
    float* __restrict__ out_feat) {
  __shared__ float ylds[4][64];
  __shared__ int   blds[4][64];
  const int tid = threadIdx.x;
  const int lane = tid & 63, wid = tid >> 6;

  // per-lane weight rows + folded BN consts
  float4 w1v[16], w2av[16], w2bv[16];
  const float4* W1r = (const float4*)(W1 + lane * 64);
  const float4* W2ar = (const float4*)(W2 + lane * 64);
  const float4* W2br = (const float4*)(W2 + (lane + 64) * 64);
#pragma unroll
  for (int i = 0; i < 16; i++) { w1v[i] = W1r[i]; w2av[i] = W2ar[i]; w2bv[i] = W2br[i]; }
  const float4 A = ((const float4*)wsp)[lane];
  const float sc1l = wsp[256 + lane], sh1l = wsp[320 + lane];
  const float sc2al = wsp[384 + lane], sh2al = wsp[512 + lane];
  const float sc2bl = wsp[448 + lane], sh2bl = wsp[576 + lane];

  for (int qi = 0; qi < QPW; qi++) {
    const int q = blockIdx.x * (4 * QPW) + qi * 4 + wid;
    const int b = q >> 11, p = q & 2047;

    const float cx = new_xyz[(size_t)q * 3 + 0];
    const float cy = new_xyz[(size_t)q * 3 + 1];
    const float cz = new_xyz[(size_t)q * 3 + 2];
    const float hc = A.w - (A.x * cx + A.y * cy + A.z * cz);

    blds[wid][lane] = ball[(size_t)q * NSAMPLE + lane];
    const float* szb = szp + (size_t)b * NPTS * 64;
    __builtin_amdgcn_s_waitcnt(0);   // vm+lgkm: blds visible to own wave

    float vA = 0.f, vB = 0.f;        // post-relu values are >= 0
    int idx0 = blds[wid][0];
    float fcur = szb[(size_t)idx0 * 64 + lane];
    const float4* yv = (const float4*)ylds[wid];

    for (int s = 0; s < NSAMPLE; s++) {
      // prefetch next sample's channel value
      int sn = (s < NSAMPLE - 1) ? s + 1 : s;
      int idxn = blds[wid][sn];
      float fnext = szb[(size_t)idxn * 64 + lane];

      // L0 epilogue
      float y0 = fmaxf(fcur + hc, 0.f);
      ylds[wid][lane] = y0;
      // L1: dot(w1_row, y0[all lanes]) via uniform float4 broadcasts
      float a0 = 0.f, a1 = 0.f, a2 = 0.f, a3 = 0.f;
#pragma unroll
      for (int i = 0; i < 16; i++) {
        float4 y = yv[i];
        a0 = fmaf(w1v[i].x, y.x, a0);
        a1 = fmaf(w1v[i].y, y.y, a1);
        a2 = fmaf(w1v[i].z, y.z, a2);
        a3 = fmaf(w1v[i].w, y.w, a3);
      }
      float y1 = fmaxf(fmaf((a0 + a1) + (a2 + a3), sc1l, sh1l), 0.f);
      ylds[wid][lane] = y1;
      // L2: two output rows per lane, shared broadcast reads
      float c0 = 0.f, c1 = 0.f, c2 = 0.f, c3 = 0.f;
      float e0 = 0.f, e1 = 0.f, e2 = 0.f, e3 = 0.f;
#pragma unroll
      for (int i = 0; i < 16; i++) {
        float4 y = yv[i];
        c0 = fmaf(w2av[i].x, y.x, c0);
        c1 = fmaf(w2av[i].y, y.y, c1);
        c2 = fmaf(w2av[i].z, y.z, c2);
        c3 = fmaf(w2av[i].w, y.w, c3);
        e0 = fmaf(w2bv[i].x, y.x, e0);
        e1 = fmaf(w2bv[i].y, y.y, e1);
        e2 = fmaf(w2bv[i].z, y.z, e2);
        e3 = fmaf(w2bv[i].w, y.w, e3);
      }
      float y2a = fmaxf(fmaf((c0 + c1) + (c2 + c3), sc2al, sh2al), 0.f);
      float y2b = fmaxf(fmaf((e0 + e1) + (e2 + e3), sc2bl, sh2bl), 0.f);
      vA = fmaxf(vA, y2a);
      vB = fmaxf(vB, y2b);
      fcur = fnext;
    }
    out_feat[((size_t)b * C2 + lane) * NPOINT + p] = vA;
    out_feat[((size_t)b * C2 + lane + 64) * NPOINT + p] = vB;
  }
}

extern "C" void kernel_launch(void* const* d_in, const int* in_sizes, int n_in,
                              void* d_out, int out_size, void* d_ws, size_t ws_size,
                              hipStream_t stream) {
  const float* xyz  = (const float*)d_in[0];
  const float* feat = (const float*)d_in[1];
  const float* W0 = (const float*)d_in[2];
  const float* g0 = (const float*)d_in[3];
  const float* b0 = (const float*)d_in[4];
  const float* m0 = (const float*)d_in[5];
  const float* v0 = (const float*)d_in[6];
  const float* W1 = (const float*)d_in[7];
  const float* g1 = (const float*)d_in[8];
  const float* b1 = (const float*)d_in[9];
  const float* m1 = (const float*)d_in[10];
  const float* v1 = (const float*)d_in[11];
  const float* W2 = (const float*)d_in[12];
  const float* g2 = (const float*)d_in[13];
  const float* b2 = (const float*)d_in[14];
  const float* m2 = (const float*)d_in[15];
  const float* v2 = (const float*)d_in[16];

  float* out = (float*)d_out;
  float* out_xyz  = out;                         // (8,2048,3)   = 49152
  float* out_feat = out + 49152;                 // (8,128,2048) = 2097152
  float* out_inds = out + 49152 + 2097152;       // (8,2048)     = 16384

  int*   ball = (int*)d_ws;                                      // 4 MiB
  float* szp  = (float*)((char*)d_ws + 4194304);                 // 16.8 MiB
  float* wsp  = (float*)((char*)d_ws + 20971520);                // ~3 KiB

  hipLaunchKernelGGL(prep_kernel, dim3(1), dim3(128), 0, stream,
                     W0, g0, b0, m0, v0, g1, b1, m1, v1, g2, b2, m2, v2, wsp);
  hipLaunchKernelGGL(zfeat_kernel, dim3(BATCH * (NPTS / 64)), dim3(256), 0, stream,
                     xyz, feat, W0, wsp, szp);
  hipLaunchKernelGGL(fps_kernel, dim3(BATCH), dim3(512), 0, stream,
                     xyz, out_xyz, out_inds);
  hipLaunchKernelGGL(ballq_kernel, dim3((BATCH * NPOINT) / 4), dim3(256), 0, stream,
                     xyz, out_xyz, ball);
  hipLaunchKernelGGL(mlp_kernel, dim3((BATCH * NPOINT) / (4 * QPW)), dim3(256), 0, stream,
                     szp, ball, out_xyz, W1, W2, wsp, out_feat);
}

// Round 6
// 3926.551 us; speedup vs baseline: 1.5189x; 1.0779x over previous
//
#include <hip/hip_runtime.h>
#include <cstdint>
#include <cstddef>

#define BATCH   8
#define NPTS    8192
#define NPOINT  2048
#define NSAMPLE 64
#define K0      67      // 3 + 64 input channels
#define C2      128

// Exact-order squared distance, matching XLA/numpy: ((dx*dx + dy*dy) + dz*dz),
// separate mul/add (no FMA contraction), round-to-nearest f32.
__device__ __forceinline__ float d2e(float ax, float ay, float az,
                                     float bx, float by, float bz) {
#pragma clang fp contract(off)
  float dx = ax - bx;
  float dy = ay - by;
  float dz = az - bz;
  float t0 = dx * dx;
  float t1 = dy * dy;
  float t2 = dz * dz;
  return (t0 + t1) + t2;
}

// ---- wave64 reductions via DPP (VALU latency ~8cy/step vs ds_permute ~50cy).
// Sequence: quad xor1, quad xor2, half-row cross, row cross, bcast15, bcast31;
// lane 63 then holds the full-wave result -> readlane broadcast (uniform).
__device__ __forceinline__ float dpp_max_f32(float x) {
  int v;
  v = __builtin_amdgcn_update_dpp(__float_as_int(x), __float_as_int(x), 0xB1, 0xF, 0xF, false);
  x = fmaxf(x, __int_as_float(v));
  v = __builtin_amdgcn_update_dpp(__float_as_int(x), __float_as_int(x), 0x4E, 0xF, 0xF, false);
  x = fmaxf(x, __int_as_float(v));
  v = __builtin_amdgcn_update_dpp(__float_as_int(x), __float_as_int(x), 0x141, 0xF, 0xF, false);
  x = fmaxf(x, __int_as_float(v));
  v = __builtin_amdgcn_update_dpp(__float_as_int(x), __float_as_int(x), 0x140, 0xF, 0xF, false);
  x = fmaxf(x, __int_as_float(v));
  v = __builtin_amdgcn_update_dpp(__float_as_int(x), __float_as_int(x), 0x142, 0xA, 0xF, false);
  x = fmaxf(x, __int_as_float(v));
  v = __builtin_amdgcn_update_dpp(__float_as_int(x), __float_as_int(x), 0x143, 0xC, 0xF, false);
  x = fmaxf(x, __int_as_float(v));
  return __int_as_float(__builtin_amdgcn_readlane(__float_as_int(x), 63));
}

__device__ __forceinline__ int dpp_min_i32(int x) {
  int v;
  v = __builtin_amdgcn_update_dpp(x, x, 0xB1, 0xF, 0xF, false); x = min(x, v);
  v = __builtin_amdgcn_update_dpp(x, x, 0x4E, 0xF, 0xF, false); x = min(x, v);
  v = __builtin_amdgcn_update_dpp(x, x, 0x141, 0xF, 0xF, false); x = min(x, v);
  v = __builtin_amdgcn_update_dpp(x, x, 0x140, 0xF, 0xF, false); x = min(x, v);
  v = __builtin_amdgcn_update_dpp(x, x, 0x142, 0xA, 0xF, false); x = min(x, v);
  v = __builtin_amdgcn_update_dpp(x, x, 0x143, 0xC, 0xF, false); x = min(x, v);
  return __builtin_amdgcn_readlane(x, 63);
}

// quartile of N(0,1)
__device__ __forceinline__ int quant4(float v) {
  return (v < -0.6745f) ? 0 : (v < 0.f) ? 1 : (v < 0.6745f) ? 2 : 3;
}

// ---------------- FPS: bucket-pruned serial argmax, DPP reduces --------------
// One block/batch. Points counting-sorted into 128 chunks of 64 ("buckets")
// by serpentine-ordered 4x4x4 quartile cells. Wave w owns buckets w*16+j,
// lane l owns sorted slot bucket*64+l. Prune: bucket skippable iff
// dist(q,c_b) > r_b + sqrt(gmax) (slack >> f32 rounding) -> dd bit-exact.
__global__ __launch_bounds__(512) void fps_kernel(const float* __restrict__ xyz,
                                                  float* __restrict__ out_xyz,
                                                  float* __restrict__ out_inds) {
  const int b = blockIdx.x;
  const int tid = threadIdx.x;
  const int lane = tid & 63, w = tid >> 6;

  __shared__ float2 sxy[NPTS];                  // ORIGINAL order (q lookup)
  __shared__ float  szl[NPTS];
  __shared__ int    soi[NPTS];                  // sorted slot -> orig idx
  __shared__ float4 bgeo[128];                  // cx,cy,cz,rb  [w*16+j]
  __shared__ unsigned long long wred[2][8] __attribute__((aligned(16)));
  __shared__ int hist[64], cbase[64], ccnt[64];

  const float* xb = xyz + (size_t)b * NPTS * 3;

  if (tid < 64) { hist[tid] = 0; ccnt[tid] = 0; }
  __syncthreads();

  // --- stage coords (original order) + histogram of serpentine quartile cells
  int lc[16];
#pragma unroll
  for (int k = 0; k < 16; k++) {
    int i = tid + k * 512;
    float x = xb[i * 3 + 0], y = xb[i * 3 + 1], z = xb[i * 3 + 2];
    sxy[i] = make_float2(x, y); szl[i] = z;
    int qx_ = quant4(x), qy_ = quant4(y), qz_ = quant4(z);
    int yy = (qx_ & 1) ? 3 - qy_ : qy_;
    int zz = ((qx_ ^ yy) & 1) ? 3 - qz_ : qz_;
    int cell = qx_ * 16 + yy * 4 + zz;
    lc[k] = cell;
    atomicAdd(&hist[cell], 1);
  }
  __syncthreads();
  if (tid == 0) {
    int s = 0;
    for (int c = 0; c < 64; c++) { cbase[c] = s; s += hist[c]; }
  }
  __syncthreads();
#pragma unroll
  for (int k = 0; k < 16; k++) {
    int pos = cbase[lc[k]] + atomicAdd(&ccnt[lc[k]], 1);
    soi[pos] = tid + k * 512;
  }
  __syncthreads();

  const float2 q0xy = sxy[0];
  const float q0x = q0xy.x, q0y = q0xy.y, q0z = szl[0];

  // --- gather owned points to regs, init dd, bucket geometry
  float px[16], py[16], pz[16], dd[16];
  int oi[16];
#pragma unroll
  for (int j = 0; j < 16; j++) {
    int s = (w * 16 + j) * 64 + lane;
    int o = soi[s];
    oi[j] = o;
    float2 pxy = sxy[o];
    px[j] = pxy.x; py[j] = pxy.y; pz[j] = szl[o];
    dd[j] = d2e(px[j], py[j], pz[j], q0x, q0y, q0z);
    float xhi = dpp_max_f32(px[j]), xlo = -dpp_max_f32(-px[j]);
    float yhi = dpp_max_f32(py[j]), ylo = -dpp_max_f32(-py[j]);
    float zhi = dpp_max_f32(pz[j]), zlo = -dpp_max_f32(-pz[j]);
    float cx = 0.5f * (xlo + xhi), cy = 0.5f * (ylo + yhi), cz = 0.5f * (zlo + zhi);
    float r2 = dpp_max_f32(d2e(px[j], py[j], pz[j], cx, cy, cz));
    float rb = sqrtf(r2) * 1.0002f + 1e-6f;      // certified over-estimate
    if (lane == 0) bgeo[w * 16 + j] = make_float4(cx, cy, cz, rb);
  }
  if (tid == 0) {
    out_inds[b * NPOINT] = 0.f;
    out_xyz[(size_t)b * NPOINT * 3 + 0] = q0x;
    out_xyz[(size_t)b * NPOINT * 3 + 1] = q0y;
    out_xyz[(size_t)b * NPOINT * 3 + 2] = q0z;
  }

  // --- initial wave key: per-thread tie-aware scan + DPP reduces
  unsigned long long wkey;
  {
    float bv = dd[0]; int boi = oi[0];
#pragma unroll
    for (int j = 1; j < 16; j++) {
      bool better = (dd[j] > bv) || (dd[j] == bv && oi[j] < boi);
      bv = better ? dd[j] : bv; boi = better ? oi[j] : boi;
    }
    float vm = dpp_max_f32(bv);
    int ci = (bv == vm) ? boi : 0x7FFFFFFF;
    int widx = dpp_min_i32(ci);
    wkey = ((unsigned long long)(~__float_as_uint(vm)) << 32) | (unsigned)widx;
  }
  if (lane == 0) wred[0][w] = wkey;
  __syncthreads();

  for (int t = 1; t < NPOINT; ++t) {
    // --- global winner = min of 8 wave keys (vectorized broadcast reads)
    const ulonglong2* wv = (const ulonglong2*)wred[(t - 1) & 1];
    ulonglong2 p0 = wv[0], p1 = wv[1], p2 = wv[2], p3 = wv[3];
    unsigned long long g0 = (p0.y < p0.x) ? p0.y : p0.x;
    unsigned long long g1 = (p1.y < p1.x) ? p1.y : p1.x;
    unsigned long long g2 = (p2.y < p2.x) ? p2.y : p2.x;
    unsigned long long g3 = (p3.y < p3.x) ? p3.y : p3.x;
    g0 = (g1 < g0) ? g1 : g0; g2 = (g3 < g2) ? g3 : g2;
    g0 = (g2 < g0) ? g2 : g0;
    const int nxt = (int)(g0 & 0xFFFFFFFFu);
    const float gmax = __uint_as_float(~(unsigned)(g0 >> 32));
    const float2 qxy = sxy[nxt];
    const float qx = qxy.x, qy = qxy.y, qz = szl[nxt];
    if (tid == 0) {
      out_inds[b * NPOINT + t] = (float)nxt;
      out_xyz[((size_t)b * NPOINT + t) * 3 + 0] = qx;
      out_xyz[((size_t)b * NPOINT + t) * 3 + 1] = qy;
      out_xyz[((size_t)b * NPOINT + t) * 3 + 2] = qz;
    }

    // --- prune check: lane jj tests bucket w*16+jj against uniform bound
    const float sg = sqrtf(gmax);
    const int jj = lane & 15;
    float4 g = bgeo[w * 16 + jj];
    float d2c = d2e(qx, qy, qz, g.x, g.y, g.z);
    float T = (g.w + sg) * 1.0005f + 1e-6f;
    bool dirty = !(d2c > T * T);
    unsigned dmask = (unsigned)__ballot(dirty) & 0xFFFFu;

    if (dmask) {
      // --- update dirty buckets + inline tie-aware scan over all 16
      float bv; int boi;
      if (dmask & 1u) dd[0] = fminf(dd[0], d2e(px[0], py[0], pz[0], qx, qy, qz));
      bv = dd[0]; boi = oi[0];
#pragma unroll
      for (int j = 1; j < 16; j++) {
        if (dmask & (1u << j))
          dd[j] = fminf(dd[j], d2e(px[j], py[j], pz[j], qx, qy, qz));
        bool better = (dd[j] > bv) || (dd[j] == bv && oi[j] < boi);
        bv = better ? dd[j] : bv; boi = better ? oi[j] : boi;
      }
      float vm = dpp_max_f32(bv);
      int ci = (bv == vm) ? boi : 0x7FFFFFFF;
      int widx = dpp_min_i32(ci);
      wkey = ((unsigned long long)(~__float_as_uint(vm)) << 32) | (unsigned)widx;
    }
    if (lane == 0) wred[t & 1][w] = wkey;
    __syncthreads();
  }
}

// ---------------- prep: fold BN into per-channel consts ----------------------
// wsp floats: [0..255] A4[o]={sc0*W0x,sc0*W0y,sc0*W0z,sh0}; [256..319] sc1;
// [320..383] sh1; [384..511] sc2; [512..639] sh2; [640..703] sc0
__global__ __launch_bounds__(128) void prep_kernel(
    const float* __restrict__ W0, const float* __restrict__ g0,
    const float* __restrict__ b0, const float* __restrict__ m0,
    const float* __restrict__ v0, const float* __restrict__ g1,
    const float* __restrict__ b1, const float* __restrict__ m1,
    const float* __restrict__ v1, const float* __restrict__ g2,
    const float* __restrict__ b2, const float* __restrict__ m2,
    const float* __restrict__ v2, float* __restrict__ wsp) {
  const int tid = threadIdx.x;
  if (tid < 64) {
    float s0 = g0[tid] / sqrtf(v0[tid] + 1e-5f);
    wsp[4 * tid + 0] = s0 * W0[tid * K0 + 0];
    wsp[4 * tid + 1] = s0 * W0[tid * K0 + 1];
    wsp[4 * tid + 2] = s0 * W0[tid * K0 + 2];
    wsp[4 * tid + 3] = b0[tid] - m0[tid] * s0;
    wsp[640 + tid] = s0;
    float s1 = g1[tid] / sqrtf(v1[tid] + 1e-5f);
    wsp[256 + tid] = s1; wsp[320 + tid] = b1[tid] - m1[tid] * s1;
  }
  float s2 = g2[tid] / sqrtf(v2[tid] + 1e-5f);
  wsp[384 + tid] = s2; wsp[512 + tid] = b2[tid] - m2[tid] * s2;
}

// ---------------- zfeat: per-point L0 linear part ----------------------------
// szp[n][o] = sc0[o] * ( W0[o][0:3] . p_xyz + W0[o][3:67] . feat[:,n] )
__global__ __launch_bounds__(256) void zfeat_kernel(const float* __restrict__ xyz,
                                                    const float* __restrict__ feat,
                                                    const float* __restrict__ W0,
                                                    const float* __restrict__ wsp,
                                                    float* __restrict__ szp) {
  __shared__ float ftile[64][64];   // [c][u] - reads are wave-uniform
  __shared__ float sxyz[192];
  const int bt = blockIdx.x;        // b*128 + nt
  const int b = bt >> 7, nt = bt & 127;
  const int tid = threadIdx.x;
  const int lane = tid & 63, w = tid >> 6;

  const float* fb = feat + (size_t)b * 64 * NPTS + (size_t)nt * 64;
#pragma unroll
  for (int r = w; r < 64; r += 4)
    ftile[r][lane] = fb[(size_t)r * NPTS + lane];
  if (tid < 192)
    sxyz[tid] = xyz[((size_t)b * NPTS + (size_t)nt * 64) * 3 + tid];

  float w0x = W0[lane * K0 + 0], w0y = W0[lane * K0 + 1], w0z = W0[lane * K0 + 2];
  float wf[64];
#pragma unroll
  for (int i = 0; i < 64; i++) wf[i] = W0[lane * K0 + 3 + i];
  const float s0 = wsp[640 + lane];
  __syncthreads();

  float* ob = szp + ((size_t)b * NPTS + (size_t)nt * 64) * 64;
  for (int u = w; u < 64; u += 4) {
    float acc = w0x * sxyz[u * 3 + 0] + w0y * sxyz[u * 3 + 1] + w0z * sxyz[u * 3 + 2];
#pragma unroll
    for (int i = 0; i < 64; i++) acc = fmaf(wf[i], ftile[i][u], acc);
    ob[(size_t)u * 64 + lane] = acc * s0;
  }
}

// ---------------- ball query: one wave per query point -----------------------
__global__ __launch_bounds__(256) void ballq_kernel(const float* __restrict__ xyz,
                                                    const float* __restrict__ new_xyz,
                                                    int* __restrict__ ball) {
  const int lane = threadIdx.x & 63;
  const int q = blockIdx.x * 4 + (threadIdx.x >> 6);
  const int b = q >> 11;
  const float RR = (float)(0.4 * 0.4);
  const float cx = new_xyz[(size_t)q * 3 + 0];
  const float cy = new_xyz[(size_t)q * 3 + 1];
  const float cz = new_xyz[(size_t)q * 3 + 2];
  const float* xb = xyz + (size_t)b * NPTS * 3;
  int cnt = 0, firsti = -1;
  for (int base = 0; base < NPTS; base += 64) {
    int i = base + lane;
    float xx = xb[i * 3 + 0], yy = xb[i * 3 + 1], zz = xb[i * 3 + 2];
    float d2 = d2e(xx, yy, zz, cx, cy, cz);
    bool m = d2 < RR;
    unsigned long long mask = __ballot(m);
    if (mask) {
      if (firsti < 0) firsti = base + (__ffsll((unsigned long long)mask) - 1);
      int pos = cnt + (int)__popcll(mask & ((1ull << lane) - 1ull));
      if (m && pos < NSAMPLE) ball[(size_t)q * NSAMPLE + pos] = i;
      cnt += (int)__popcll(mask);
      if (cnt >= NSAMPLE) break;
    }
  }
  for (int s = cnt + lane; s < NSAMPLE; s += 64)
    ball[(size_t)q * NSAMPLE + s] = firsti;
}

// ---------------- MLP L1/L2 + max-pool: lane = channel, loop samples ---------
#define QPW 4
__global__ __launch_bounds__(256, 2) void mlp_kernel(
    const float* __restrict__ szp, const int* __restrict__ ball,
    const float* __restrict__ new_xyz, const float* __restrict__ W1,
    const float* __restrict__ W2, const float* __restrict__ wsp,
    float* __restrict__ out_feat) {
  __shared__ float ylds[4][64];
  __shared__ int   blds[4][64];
  const int tid = threadIdx.x;
  const int lane = tid & 63, wid = tid >> 6;

  float4 w1v[16], w2av[16], w2bv[16];
  const float4* W1r = (const float4*)(W1 + lane * 64);
  const float4* W2ar = (const float4*)(W2 + lane * 64);
  const float4* W2br = (const float4*)(W2 + (lane + 64) * 64);
#pragma unroll
  for (int i = 0; i < 16; i++) { w1v[i] = W1r[i]; w2av[i] = W2ar[i]; w2bv[i] = W2br[i]; }
  const float4 A = ((const float4*)wsp)[lane];
  const float sc1l = wsp[256 + lane], sh1l = wsp[320 + lane];
  const float sc2al = wsp[384 + lane], sh2al = wsp[512 + lane];
  const float sc2bl = wsp[448 + lane], sh2bl = wsp[576 + lane];

  for (int qi = 0; qi < QPW; qi++) {
    const int q = blockIdx.x * (4 * QPW) + qi * 4 + wid;
    const int b = q >> 11, p = q & 2047;

    const float cx = new_xyz[(size_t)q * 3 + 0];
    const float cy = new_xyz[(size_t)q * 3 + 1];
    const float cz = new_xyz[(size_t)q * 3 + 2];
    const float hc = A.w - (A.x * cx + A.y * cy + A.z * cz);

    blds[wid][lane] = ball[(size_t)q * NSAMPLE + lane];
    const float* szb = szp + (size_t)b * NPTS * 64;
    __builtin_amdgcn_s_waitcnt(0);   // vm+lgkm: blds visible to own wave

    float vA = 0.f, vB = 0.f;
    int idx0 = blds[wid][0];
    float fcur = szb[(size_t)idx0 * 64 + lane];
    const float4* yv = (const float4*)ylds[wid];

    for (int s = 0; s < NSAMPLE; s++) {
      int sn = (s < NSAMPLE - 1) ? s + 1 : s;
      int idxn = blds[wid][sn];
      float fnext = szb[(size_t)idxn * 64 + lane];

      float y0 = fmaxf(fcur + hc, 0.f);
      ylds[wid][lane] = y0;
      float a0 = 0.f, a1 = 0.f, a2 = 0.f, a3 = 0.f;
#pragma unroll
      for (int i = 0; i < 16; i++) {
        float4 y = yv[i];
        a0 = fmaf(w1v[i].x, y.x, a0);
        a1 = fmaf(w1v[i].y, y.y, a1);
        a2 = fmaf(w1v[i].z, y.z, a2);
        a3 = fmaf(w1v[i].w, y.w, a3);
      }
      float y1 = fmaxf(fmaf((a0 + a1) + (a2 + a3), sc1l, sh1l), 0.f);
      ylds[wid][lane] = y1;
      float c0 = 0.f, c1 = 0.f, c2 = 0.f, c3 = 0.f;
      float e0 = 0.f, e1 = 0.f, e2 = 0.f, e3 = 0.f;
#pragma unroll
      for (int i = 0; i < 16; i++) {
        float4 y = yv[i];
        c0 = fmaf(w2av[i].x, y.x, c0);
        c1 = fmaf(w2av[i].y, y.y, c1);
        c2 = fmaf(w2av[i].z, y.z, c2);
        c3 = fmaf(w2av[i].w, y.w, c3);
        e0 = fmaf(w2bv[i].x, y.x, e0);
        e1 = fmaf(w2bv[i].y, y.y, e1);
        e2 = fmaf(w2bv[i].z, y.z, e2);
        e3 = fmaf(w2bv[i].w, y.w, e3);
      }
      float y2a = fmaxf(fmaf((c0 + c1) + (c2 + c3), sc2al, sh2al), 0.f);
      float y2b = fmaxf(fmaf((e0 + e1) + (e2 + e3), sc2bl, sh2bl), 0.f);
      vA = fmaxf(vA, y2a);
      vB = fmaxf(vB, y2b);
      fcur = fnext;
    }
    out_feat[((size_t)b * C2 + lane) * NPOINT + p] = vA;
    out_feat[((size_t)b * C2 + lane + 64) * NPOINT + p] = vB;
  }
}

extern "C" void kernel_launch(void* const* d_in, const int* in_sizes, int n_in,
                              void* d_out, int out_size, void* d_ws, size_t ws_size,
                              hipStream_t stream) {
  const float* xyz  = (const float*)d_in[0];
  const float* feat = (const float*)d_in[1];
  const float* W0 = (const float*)d_in[2];
  const float* g0 = (const float*)d_in[3];
  const float* b0 = (const float*)d_in[4];
  const float* m0 = (const float*)d_in[5];
  const float* v0 = (const float*)d_in[6];
  const float* W1 = (const float*)d_in[7];
  const float* g1 = (const float*)d_in[8];
  const float* b1 = (const float*)d_in[9];
  const float* m1 = (const float*)d_in[10];
  const float* v1 = (const float*)d_in[11];
  const float* W2 = (const float*)d_in[12];
  const float* g2 = (const float*)d_in[13];
  const float* b2 = (const float*)d_in[14];
  const float* m2 = (const float*)d_in[15];
  const float* v2 = (const float*)d_in[16];

  float* out = (float*)d_out;
  float* out_xyz  = out;                         // (8,2048,3)   = 49152
  float* out_feat = out + 49152;                 // (8,128,2048) = 2097152
  float* out_inds = out + 49152 + 2097152;       // (8,2048)     = 16384

  int*   ball = (int*)d_ws;                                      // 4 MiB
  float* szp  = (float*)((char*)d_ws + 4194304);                 // 16.8 MiB
  float* wsp  = (float*)((char*)d_ws + 20971520);                // ~3 KiB

  hipLaunchKernelGGL(prep_kernel, dim3(1), dim3(128), 0, stream,
                     W0, g0, b0, m0, v0, g1, b1, m1, v1, g2, b2, m2, v2, wsp);
  hipLaunchKernelGGL(zfeat_kernel, dim3(BATCH * (NPTS / 64)), dim3(256), 0, stream,
                     xyz, feat, W0, wsp, szp);
  hipLaunchKernelGGL(fps_kernel, dim3(BATCH), dim3(512), 0, stream,
                     xyz, out_xyz, out_inds);
  hipLaunchKernelGGL(ballq_kernel, dim3((BATCH * NPOINT) / 4), dim3(256), 0, stream,
                     xyz, out_xyz, ball);
  hipLaunchKernelGGL(mlp_kernel, dim3((BATCH * NPOINT) / (4 * QPW)), dim3(256), 0, stream,
                     szp, ball, out_xyz, W1, W2, wsp, out_feat);
}